// Round 6
// baseline (244.764 us; speedup 1.0000x reference)
//
#include <hip/hip_runtime.h>
#include <hip/hip_bf16.h>

// CRF sequence labeling: B=64, S=512, H=1024, L=9
// R6: linear-domain chunk recursion (the R1-R5 hidden 79µs kernel, per the
//     cross-round duration algebra; see round-6 theory).
//   K0 wcvt_kernel   : W -> wbf[16,1024] bf16 *log2e; T2[81] = exp(trans);
//                      zeroes d_out.
//   K1 logits_kernel : feats[32768,12] = inp @ W^T via mfma_f32_16x16x32_bf16,
//                      1 M-tile/wave (2048 waves = 2/SIMD TLP). cols 9..11 = 0.
//   K2 chunk_kernel  : ONE LANE per transfer-matrix row. row' = (row·T)∘E_t in
//                      LINEAR fp32 with per-step exponent rescale (frexp/ldexp,
//                      shift accumulated). T[81] in VGPRs. No shuffles/LDS.
//   K3 final_kernel  : per batch alpha chain over P_c (log2 domain) + gold
//                      score; atomicAdd of (norm-score)*ln2/B.

#define BATCH 64
#define SEQ   512
#define HID   1024
#define NLAB  9
#define FST   12                      // feats row stride (padded for float4 x3)
#define CHUNK 32
#define NCHUNK (SEQ / CHUNK)          // 16
#define NREC (BATCH * NCHUNK * NLAB)  // 9216
#define NROWS (BATCH * SEQ)           // 32768
#define NTILES (NROWS / 16)           // 2048 M-tiles

__device__ __forceinline__ float exp2_fast(float x) { return __builtin_amdgcn_exp2f(x); }
__device__ __forceinline__ float log2_fast(float x) { return __builtin_amdgcn_logf(x); }

#define LOG2E 1.4426950408889634f
#define LN2   0.6931471805599453f

typedef __attribute__((ext_vector_type(8))) short short8;   // 8 bf16 (4 VGPRs)
typedef __attribute__((ext_vector_type(4))) float float4v;  // MFMA C/D

// ---------------------------------------------------------------------------
// K0: W -> bf16 *LOG2E zero-padded to 16 rows; T2 = exp(trans); out = 0.
// ---------------------------------------------------------------------------
__global__ __launch_bounds__(256) void wcvt_kernel(
    const float* __restrict__ W, const float* __restrict__ trans,
    __hip_bfloat16* __restrict__ wbf, float* __restrict__ T2,
    float* __restrict__ out)
{
    int idx = blockIdx.x * 256 + threadIdx.x;   // 0..16383
    int n = idx >> 10, k = idx & 1023;
    float v = (n < NLAB) ? W[n * HID + k] * LOG2E : 0.0f;
    wbf[idx] = __float2bfloat16(v);
    if (blockIdx.x == 0) {
        if (threadIdx.x < 81) T2[threadIdx.x] = exp2_fast(trans[threadIdx.x] * LOG2E);
        if (threadIdx.x == 81) out[0] = 0.0f;
    }
}

// ---------------------------------------------------------------------------
// K1: MFMA logits. 512 blocks x 256 = 2048 waves; wave = one 16-row M-tile.
// Layouts (m89/m91-verified): A[m=lane&15][k=(lane>>4)*8+j];
// B[k=(lane>>4)*8+j][n=lane&15] = wbf[n][k..k+8]; C col=lane&15,
// row=(lane>>4)*4+reg. feats stride 12, cols 9..11 zeroed.
// ---------------------------------------------------------------------------
__global__ __launch_bounds__(256) void logits_kernel(
    const float* __restrict__ inp, const __hip_bfloat16* __restrict__ wbf,
    const float* __restrict__ bias, float* __restrict__ feats)
{
    const int lane = threadIdx.x & 63;
    const int wv   = threadIdx.x >> 6;
    const int wid  = blockIdx.x * 4 + wv;        // 0..2047
    const int n    = lane & 15;
    const int q8   = lane >> 4;                  // 0..3
    const long r0  = (long)wid * 16;

    const float* ap = inp + (r0 + n) * HID + q8 * 8;
    const short* bp = (const short*)wbf + n * HID + q8 * 8;

    float4v acc = {0.f, 0.f, 0.f, 0.f};

    for (int kk = 0; kk < 32; ++kk) {
        const int ko = kk * 32;
        float x[8];
        *(float4*)(x)     = *(const float4*)(ap + ko);
        *(float4*)(x + 4) = *(const float4*)(ap + ko + 4);
        short8 bfrag = *(const short8*)(bp + ko);
        short8 af;
        #pragma unroll
        for (int j = 0; j < 8; ++j) {
            union { __hip_bfloat16 h; short s; } u;
            u.h = __float2bfloat16(x[j]);
            af[j] = u.s;
        }
        acc = __builtin_amdgcn_mfma_f32_16x16x32_bf16(af, bfrag, acc, 0, 0, 0);
    }

    if (n < FST) {
        const float bK = (n < NLAB) ? bias[n] * LOG2E : 0.0f;
        #pragma unroll
        for (int r = 0; r < 4; ++r) {
            const long row = r0 + q8 * 4 + r;
            feats[row * FST + n] = (n < NLAB) ? (acc[r] + bK) : 0.0f;
        }
    }
}

// ---------------------------------------------------------------------------
// K2: linear-domain chunk rows. 144 blocks x 64; lane rid=(b*16+c)*9+i owns
// row i of chunk-c's transfer matrix: row' = (row·T) ∘ 2^emit_t, rescaled by
// 2^-ex each step (ex accumulated in shift). Masked step = identity (select).
// Output P[rid][j] = log2(row[j]) + shift  (log2-domain, as K3 expects).
// ---------------------------------------------------------------------------
__global__ __launch_bounds__(64) void chunk_kernel(
    const float* __restrict__ feats, const float* __restrict__ T2,
    const int* __restrict__ mask, float* __restrict__ P)
{
    const int rid = blockIdx.x * 64 + threadIdx.x;   // 0..9215
    const int i  = rid % NLAB;
    const int bc = rid / NLAB;
    const int c  = bc & (NCHUNK - 1);
    const int b  = bc >> 4;

    float T[NLAB][NLAB];                 // uniform -> broadcast loads, one-time
    #pragma unroll
    for (int k = 0; k < NLAB; ++k)
        #pragma unroll
        for (int j = 0; j < NLAB; ++j) T[k][j] = T2[k * NLAB + j];

    const float* fb = feats + (long)b * SEQ * FST;
    const int* mb = mask + b * SEQ;
    const int t0 = c * CHUNK;
    const int ts = (c == 0) ? 1 : t0;
    const int te = t0 + CHUNK;

    float row[NLAB];
    #pragma unroll
    for (int k = 0; k < NLAB; ++k) row[k] = (k == i) ? 1.0f : 0.0f;
    float shift = 0.0f;

    float e[12]; int m_cur;
    {
        const float4* p = (const float4*)(fb + (long)ts * FST);
        *(float4*)(e) = p[0]; *(float4*)(e + 4) = p[1]; *(float4*)(e + 8) = p[2];
        m_cur = mb[ts];
    }

    for (int t = ts; t < te; ++t) {
        float en[12]; int m_nxt = 0;
        if (t + 1 < te) {                         // prefetch next step
            const float4* p = (const float4*)(fb + (long)(t + 1) * FST);
            *(float4*)(en) = p[0]; *(float4*)(en + 4) = p[1]; *(float4*)(en + 8) = p[2];
            m_nxt = mb[t + 1];
        }
        float nr[NLAB];
        #pragma unroll
        for (int j = 0; j < NLAB; ++j) {
            float a = row[0] * T[0][j];
            #pragma unroll
            for (int k = 1; k < NLAB; ++k) a = fmaf(row[k], T[k][j], a);
            nr[j] = a * exp2_fast(e[j]);
        }
        float mx = nr[0];
        #pragma unroll
        for (int j = 1; j < NLAB; ++j) mx = fmaxf(mx, nr[j]);
        int ex = __builtin_amdgcn_frexp_expf(mx);     // mx ~ 2^(ex-1)
        const bool upd = (m_cur > 0);
        #pragma unroll
        for (int j = 0; j < NLAB; ++j) {
            float sj = __builtin_amdgcn_ldexpf(nr[j], -ex);
            row[j] = upd ? sj : row[j];
        }
        shift = upd ? (shift + (float)ex) : shift;

        #pragma unroll
        for (int q = 0; q < 12; ++q) e[q] = en[q];
        m_cur = m_nxt;
    }

    float* Pp = P + (long)rid * NLAB;
    #pragma unroll
    for (int j = 0; j < NLAB; ++j) Pp[j] = log2_fast(row[j]) + shift;
}

// ---------------------------------------------------------------------------
// K3: per-batch finalize. Grid: 64 blocks x 64. (log2 domain, stride-12 feats)
// ---------------------------------------------------------------------------
__global__ __launch_bounds__(64) void final_kernel(
    const float* __restrict__ feats, const float* __restrict__ trans,
    const float* __restrict__ startv, const float* __restrict__ endv,
    const int* __restrict__ labels, const int* __restrict__ mask,
    const float* __restrict__ P, float* __restrict__ out)
{
    const int b = blockIdx.x, lane = threadIdx.x;
    const float* fb = feats + (long)b * SEQ * FST;
    const int* lb = labels + b * SEQ;
    const int* mb = mask + b * SEQ;

    // ---- gold score ----
    float gsum = 0.0f; int msum = 0;
    for (int t = lane; t < SEQ; t += 64) {
        int tag = lb[t];
        int mt = mb[t];
        if (mt > 0) {
            gsum += fb[t * FST + tag];
            msum++;
            if (t > 0) gsum += trans[lb[t - 1] * NLAB + tag] * LOG2E;
        }
    }
    #pragma unroll
    for (int off = 32; off > 0; off >>= 1) {
        gsum += __shfl_xor(gsum, off, 64);
        msum += __shfl_xor(msum, off, 64);
    }

    // ---- alpha chain over chunk matrices ----
    const int j = lane % 9;
    float al = fb[j] + startv[j] * LOG2E;
    const float* Pb = P + (long)b * NCHUNK * 81;
    float pc[NLAB];
    #pragma unroll
    for (int i = 0; i < NLAB; ++i) pc[i] = Pb[i * NLAB + j];
    #pragma unroll
    for (int c = 0; c < NCHUNK; ++c) {
        float pn[NLAB];
        if (c < NCHUNK - 1) {
            #pragma unroll
            for (int i = 0; i < NLAB; ++i) pn[i] = Pb[(c + 1) * 81 + i * NLAB + j];
        } else {
            #pragma unroll
            for (int i = 0; i < NLAB; ++i) pn[i] = 0.0f;
        }
        float v[NLAB];
        #pragma unroll
        for (int i = 0; i < NLAB; ++i) v[i] = __shfl(al, i, 64) + pc[i];
        float m01 = fmaxf(v[0], v[1]), m23 = fmaxf(v[2], v[3]);
        float m45 = fmaxf(v[4], v[5]), m67 = fmaxf(v[6], v[7]);
        float mx = fmaxf(fmaxf(fmaxf(m01, m23), fmaxf(m45, m67)), v[8]);
        float s = 0.0f;
        #pragma unroll
        for (int i = 0; i < NLAB; ++i) s += exp2_fast(v[i] - mx);
        al = mx + log2_fast(s);
        #pragma unroll
        for (int i = 0; i < NLAB; ++i) pc[i] = pn[i];
    }
    al += endv[j] * LOG2E;

    float v[NLAB];
    #pragma unroll
    for (int i = 0; i < NLAB; ++i) v[i] = __shfl(al, i, 64);
    float m01 = fmaxf(v[0], v[1]), m23 = fmaxf(v[2], v[3]);
    float m45 = fmaxf(v[4], v[5]), m67 = fmaxf(v[6], v[7]);
    float mx = fmaxf(fmaxf(fmaxf(m01, m23), fmaxf(m45, m67)), v[8]);
    float s = 0.0f;
    #pragma unroll
    for (int i = 0; i < NLAB; ++i) s += exp2_fast(v[i] - mx);
    float norm = mx + log2_fast(s);

    if (lane == 0) {
        int li = (msum > 0) ? (msum - 1) : 0;
        float score = gsum + startv[lb[0]] * LOG2E + endv[lb[li]] * LOG2E;
        atomicAdd(out, (norm - score) * (LN2 / (float)BATCH));
    }
}

extern "C" void kernel_launch(void* const* d_in, const int* in_sizes, int n_in,
                              void* d_out, int out_size, void* d_ws, size_t ws_size,
                              hipStream_t stream)
{
    const float* inp    = (const float*)d_in[0];
    const int*   labels = (const int*)d_in[1];
    const int*   mask   = (const int*)d_in[2];
    const float* W      = (const float*)d_in[3];
    const float* bias   = (const float*)d_in[4];
    const float* trans  = (const float*)d_in[5];
    const float* startv = (const float*)d_in[6];
    const float* endv   = (const float*)d_in[7];

    float* feats = (float*)d_ws;                          // 32768*12 floats
    float* P     = feats + (long)NROWS * FST;             // 82944 floats
    float* T2    = P + (long)BATCH * NCHUNK * 81;         // 81 floats
    __hip_bfloat16* wbf = (__hip_bfloat16*)(T2 + 128);    // 16384 bf16
    float* out   = (float*)d_out;

    hipLaunchKernelGGL(wcvt_kernel, dim3(64), dim3(256), 0, stream,
                       W, trans, wbf, T2, out);
    hipLaunchKernelGGL(logits_kernel, dim3(NTILES / 4), dim3(256), 0, stream,
                       inp, wbf, bias, feats);
    hipLaunchKernelGGL(chunk_kernel, dim3(NREC / 64), dim3(64), 0, stream,
                       feats, T2, mask, P);
    hipLaunchKernelGGL(final_kernel, dim3(BATCH), dim3(64), 0, stream,
                       feats, trans, startv, endv, labels, mask, P, out);
}